// Round 1
// 1089.433 us; speedup vs baseline: 1.3352x; 1.3352x over previous
//
#include <hip/hip_runtime.h>

// NonLocalMeans: rgb (8,3,1024,1024) f32, search 11x11, patch 5x5, circular.
// out(p) = sum_s w(p,s)*rgb(p-s) / sum_s w(p,s),
// w(p,s) = exp(-sqrt(box5x5((y - y_shift)^2)) * inv_h)
//
// R1/R2 lesson: local arrays were not promoted (scratch HBM traffic).
// R3 lesson (this version): even with zero allocas, the allocator capped at
// 64 VGPRs (targeting 8 waves/EU) and spilled ~5.8 GB to scratch -- but LDS
// (37 KB/block) caps occupancy at 4 blocks/CU = 4 waves/SIMD regardless, so
// the 64-cap bought nothing. Fix:
//   (a) pin amdgpu_waves_per_eu(4,4) -> 128-VGPR budget (LDS-implied occupancy)
//   (b) replace the 5-row ring of horizontal sums (55 live floats) with
//       partial vertical accumulators (44 live), finalizing each output row
//       the moment its 5th patch row lands. Same summation order (ascending
//       rows, identical fmaf chains) -> bit-identical output.
//   All values are token-pasted named scalars; nothing can be an alloca.

#define HW (1024 * 1024)
#define W 1024
#define MASK 1023

constexpr int TILE = 32;
constexpr int YREG = 46;    // TILE + 2*7 (shift 5 + patch 2)
constexpr int YPITCH = 48;
constexpr int CREG = 42;    // TILE + 2*5
// -log2(e) / (1.0 + 1e-6)
constexpr float NEG_C = -1.4426935981939074f;

// squared-diff 5-tap horizontal sum; c0..c4 in scope at expansion site
#define SQ5(W0,W1,W2,W3,W4) \
    fmaf(c4-(W4), c4-(W4), fmaf(c3-(W3), c3-(W3), fmaf(c2-(W2), c2-(W2), \
    fmaf(c1-(W1), c1-(W1), (c0-(W0))*(c0-(W0))))))

// Load row r = y0-2+RR (LDS row y0+5+RR) and its dy-shifted counterpart,
// produce h0..h10 = horizontal 5-sums of squared diffs for dx = 5-J.
// NOT do-while wrapped: h0..h10 must stay in scope for VSET/VADD.
#define ROW_H(RR)                                                           \
    const float* ycp = &ldsY[(y0 + 5 + (RR)) * YPITCH + tx + 5];            \
    const float* ywp = &ldsY[(y0 + 5 + (RR) - dy) * YPITCH + tx];           \
    const float c0=ycp[0],c1=ycp[1],c2=ycp[2],c3=ycp[3],c4=ycp[4];          \
    const float w0 =ywp[0], w1 =ywp[1], w2 =ywp[2], w3 =ywp[3], w4 =ywp[4]; \
    const float w5 =ywp[5], w6 =ywp[6], w7 =ywp[7], w8 =ywp[8], w9 =ywp[9]; \
    const float w10=ywp[10],w11=ywp[11],w12=ywp[12],w13=ywp[13],w14=ywp[14];\
    const float h0  = SQ5(w10,w11,w12,w13,w14);                             \
    const float h1  = SQ5(w9, w10,w11,w12,w13);                             \
    const float h2  = SQ5(w8, w9, w10,w11,w12);                             \
    const float h3  = SQ5(w7, w8, w9, w10,w11);                             \
    const float h4  = SQ5(w6, w7, w8, w9, w10);                             \
    const float h5  = SQ5(w5, w6, w7, w8, w9);                              \
    const float h6  = SQ5(w4, w5, w6, w7, w8);                              \
    const float h7  = SQ5(w3, w4, w5, w6, w7);                              \
    const float h8  = SQ5(w2, w3, w4, w5, w6);                              \
    const float h9  = SQ5(w1, w2, w3, w4, w5);                              \
    const float h10 = SQ5(w0, w1, w2, w3, w4);

// partial vertical box-sum accumulators, 11 per output row, named scalars
#define VDECL(VD) float VD##_0, VD##_1, VD##_2, VD##_3, VD##_4, VD##_5,     \
                        VD##_6, VD##_7, VD##_8, VD##_9, VD##_10
#define VSET(VD)  VD##_0 =h0; VD##_1 =h1; VD##_2 =h2; VD##_3 =h3;           \
                  VD##_4 =h4; VD##_5 =h5; VD##_6 =h6; VD##_7 =h7;           \
                  VD##_8 =h8; VD##_9 =h9; VD##_10=h10
#define VADD(VD)  VD##_0 +=h0; VD##_1 +=h1; VD##_2 +=h2; VD##_3 +=h3;       \
                  VD##_4 +=h4; VD##_5 +=h5; VD##_6 +=h6; VD##_7 +=h7;       \
                  VD##_8 +=h8; VD##_9 +=h9; VD##_10+=h10

#define FIN1(YO, VD, J) do {                                                \
    float dist = __builtin_amdgcn_sqrtf(VD##_##J);                          \
    float wgt  = __builtin_amdgcn_exp2f(dist * NEG_C);                      \
    float4 px = crow[-(J)];                                                 \
    aR##YO = fmaf(wgt, px.x, aR##YO);                                       \
    aG##YO = fmaf(wgt, px.y, aG##YO);                                       \
    aB##YO = fmaf(wgt, px.z, aB##YO);                                       \
    aW##YO += wgt;                                                          \
} while (0)

// output row YO complete for this dy: weight + rgb accumulation, frees VD
#define FIN(YO, VD) do {                                                    \
    const float4* crow = &ldsC[(y0 + (YO) - dy + 5) * CREG + tx + 10];      \
    FIN1(YO,VD,0); FIN1(YO,VD,1); FIN1(YO,VD,2); FIN1(YO,VD,3);             \
    FIN1(YO,VD,4); FIN1(YO,VD,5); FIN1(YO,VD,6); FIN1(YO,VD,7);             \
    FIN1(YO,VD,8); FIN1(YO,VD,9); FIN1(YO,VD,10);                           \
} while (0)

#define STORE(YO) do {                                                      \
    const int off = (by0 + y0 + (YO)) * W + bx0 + tx;                       \
    const float inv = 1.0f / aW##YO;                                        \
    obase[off]          = aR##YO * inv;                                     \
    obase[off + HW]     = aG##YO * inv;                                     \
    obase[off + 2 * HW] = aB##YO * inv;                                     \
} while (0)

__global__ void __launch_bounds__(256) __attribute__((amdgpu_waves_per_eu(4, 4)))
nlm_fused(const float* __restrict__ rgb, float* __restrict__ out) {
    __shared__ float  ldsY[YREG * YPITCH];      // 8832 B
    __shared__ float4 ldsC[CREG * CREG];        // 28224 B

    const int tid = threadIdx.x;
    const int batch = blockIdx.z;
    const int by0 = blockIdx.y * TILE;
    const int bx0 = blockIdx.x * TILE;

    const float* base = rgb + (size_t)batch * 3 * HW;

    // ---- stage luminance tile (mean over channels), halo 7 ----
    for (int i = tid; i < YREG * YREG; i += 256) {
        int ry = i / YREG, rx = i - ry * YREG;
        int gy = (by0 + ry - 7) & MASK;
        int gx = (bx0 + rx - 7) & MASK;
        int off = gy * W + gx;
        float v = (base[off] + base[off + HW] + base[off + 2 * HW]) * (1.0f / 3.0f);
        ldsY[ry * YPITCH + rx] = v;
    }
    // ---- stage rgb tile as float4, halo 5 ----
    for (int i = tid; i < CREG * CREG; i += 256) {
        int ry = i / CREG, rx = i - ry * CREG;
        int gy = (by0 + ry - 5) & MASK;
        int gx = (bx0 + rx - 5) & MASK;
        int off = gy * W + gx;
        ldsC[i] = make_float4(base[off], base[off + HW], base[off + 2 * HW], 0.0f);
    }
    __syncthreads();

    const int tx = tid & 31;          // output column within tile
    const int y0 = (tid >> 5) * 4;    // 4-pixel column run per thread

    float aR0=0.f, aG0=0.f, aB0=0.f, aW0=0.f;
    float aR1=0.f, aG1=0.f, aB1=0.f, aW1=0.f;
    float aR2=0.f, aG2=0.f, aB2=0.f, aW2=0.f;
    float aR3=0.f, aG3=0.f, aB3=0.f, aW3=0.f;

    #pragma clang loop unroll(disable)
    for (int dy = -5; dy <= 5; ++dy) {
        VDECL(v0); VDECL(v1); VDECL(v2); VDECL(v3);
        { ROW_H(0); VSET(v0); }
        { ROW_H(1); VADD(v0); VSET(v1); }
        { ROW_H(2); VADD(v0); VADD(v1); VSET(v2); }
        { ROW_H(3); VADD(v0); VADD(v1); VADD(v2); VSET(v3); }
        { ROW_H(4); VADD(v0); VADD(v1); VADD(v2); VADD(v3); }
        FIN(0, v0);
        { ROW_H(5); VADD(v1); VADD(v2); VADD(v3); }
        FIN(1, v1);
        { ROW_H(6); VADD(v2); VADD(v3); }
        FIN(2, v2);
        { ROW_H(7); VADD(v3); }
        FIN(3, v3);
    }

    float* obase = out + (size_t)batch * 3 * HW;
    STORE(0);
    STORE(1);
    STORE(2);
    STORE(3);
}

extern "C" void kernel_launch(void* const* d_in, const int* in_sizes, int n_in,
                              void* d_out, int out_size, void* d_ws, size_t ws_size,
                              hipStream_t stream) {
    const float* rgb = (const float*)d_in[0];
    float* out = (float*)d_out;
    dim3 grid(W / TILE, W / TILE, 8);
    dim3 block(256, 1, 1);
    hipLaunchKernelGGL(nlm_fused, grid, block, 0, stream, rgb, out);
}